// Round 8
// baseline (329.299 us; speedup 1.0000x reference)
//
#include <hip/hip_runtime.h>
#include <hip/hip_bf16.h>
#include <math.h>

// Problem constants
#define BATCH 16
#define L1 32
#define L2 128
#define DEC 512
#define MEM 512
#define TOPN 50
#define NROWS (BATCH * L1 * L2)   // 65536 word rows
#define NBQ (BATCH * L1)          // 512 (b,q) rows

typedef short short8 __attribute__((ext_vector_type(8)));
typedef float f32x16 __attribute__((ext_vector_type(16)));

// ---------------- ws layout (floats) ----------------
#define WS_WP     0          // perm bf16 Wm : 32768 slots x 16B = floats [0,131072)
#define WS_BIAS1  262144
#define WS_BIAS2  270336
#define WS_DOCSC  278528     // doc scores [512]

// packed pair via v_cvt_pk_bf16_f32
__device__ __forceinline__ unsigned int pkbf(float a, float b) {
    __hip_bfloat162 h = __float22bfloat162_rn(float2{a, b});
    union { __hip_bfloat162 h; unsigned int u; } c{h};
    return c.u;
}

__device__ __forceinline__ float fast_tanh(float x) {
    return 1.f - 2.f / (__expf(2.f * x) + 1.f);
}

// ============ kernel 0 (setup): permute Wm + bias thread-per-output + zero ctx ============
// permute slot s (16B) holds Wm[d][k..k+7] bf16: s = C*1024 + nt*64 + k8*32 + n
//   d = nt*32+n ; k = C*16 + k8*8      (layout HW-verified)
// bias: 64 blocks = (mat, b, half). Thread t -> d = half*256 + t. dec/topic staged in
// LDS (broadcast reads); weights read serially per-thread with deep unroll. No reduces.
__global__ __launch_bounds__(256) void setup_kernel(
    const float* __restrict__ Wm,
    unsigned short* __restrict__ Wp,
    const float* __restrict__ dec, const float* __restrict__ topic,
    const float* __restrict__ Wd, const float* __restrict__ Wt,
    const float* __restrict__ Wd2, const float* __restrict__ Wt2,
    float* __restrict__ bias1, float* __restrict__ bias2,
    float* __restrict__ ctx_out)
{
    const int bid = blockIdx.x;
    const int tid = threadIdx.x;
    if (bid < 128) {
        int s = bid * 256 + tid;                    // 0..32767
        int C = s >> 10;
        int u = s & 1023;
        int nt = u >> 6, k8 = (u >> 5) & 1, n_in = u & 31;
        int d = nt * 32 + n_in;
        int k = C * 16 + k8 * 8;

        const float4* src = (const float4*)(Wm + (size_t)d * DEC + k);
        float4 v0 = src[0], v1 = src[1];
        uint4 v;
        v.x = pkbf(v0.x, v0.y); v.y = pkbf(v0.z, v0.w);
        v.z = pkbf(v1.x, v1.y); v.w = pkbf(v1.z, v1.w);
        ((uint4*)Wp)[s] = v;
    } else if (bid < 128 + 64) {
        // bias: (mat, b, half) ; thread t -> d = half*256 + t
        __shared__ float sdec[DEC];
        __shared__ float stop[TOPN];
        const int u = bid - 128;            // 0..63
        const int mat = u >> 5;             // 0: bias1 (Wd,Wt), 1: bias2 (Wd2,Wt2)
        const int bb = (u >> 1) & 15;       // 0..15
        const int half = u & 1;             // 0..1
        const int d = half * 256 + tid;

        if (tid < 128) {
            float4 v = ((const float4*)(dec + (size_t)bb * DEC))[tid];
            ((float4*)sdec)[tid] = v;
        }
        if (tid >= 128 && tid < 128 + TOPN) stop[tid - 128] = topic[bb * TOPN + (tid - 128)];
        __syncthreads();

        const float* wrow = (mat ? Wd2 : Wd) + (size_t)d * DEC;
        float acc = 0.f;
#pragma unroll 8
        for (int k4 = 0; k4 < 128; ++k4) {
            float4 w = ((const float4*)wrow)[k4];
            float4 x = ((const float4*)sdec)[k4];
            acc = fmaf(w.x, x.x, acc);
            acc = fmaf(w.y, x.y, acc);
            acc = fmaf(w.z, x.z, acc);
            acc = fmaf(w.w, x.w, acc);
        }
        const float* trow = (mat ? Wt2 : Wt) + (size_t)d * TOPN;
#pragma unroll 5
        for (int t2 = 0; t2 < TOPN / 2; ++t2) {
            float2 w = ((const float2*)trow)[t2];
            acc = fmaf(w.x, stop[t2 * 2], acc);
            acc = fmaf(w.y, stop[t2 * 2 + 1], acc);
        }
        (mat ? bias2 : bias1)[bb * DEC + d] = acc;
    } else {
        // zero ctx accumulator region of d_out (8192 floats), 4 blocks
        int i = (bid - (128 + 64)) * 256 + tid;   // 0..1023
        float4 z = {0.f, 0.f, 0.f, 0.f};
        ((float4*)ctx_out)[i * 2] = z;
        ((float4*)ctx_out)[i * 2 + 1] = z;
    }
}

// ============ doc score kernel v2: block-per-2-rows, thread-per-(d,row) ============
// 256 blocks x 256 threads. X rows staged in LDS (broadcast, conflict-free).
// Thread t computes d in {t, t+256} for both rows (weight row reused across rows —
// halves L2 weight traffic). No cross-lane ops in hot loop; one block reduce at end.
__global__ __launch_bounds__(256) void doc_score_kernel(
    const float* __restrict__ Xd,     // doc_memory [512][512]
    const float* __restrict__ Wm2,    // [512][512] row-major [d][m]
    const float* __restrict__ Wv2,    // [512]
    const float* __restrict__ bias2,  // [16][512]
    float* __restrict__ doc_scores)   // [512]
{
    __shared__ float xrow0[MEM];
    __shared__ float xrow1[MEM];
    __shared__ float wsum[2][4];
    const int tid = threadIdx.x;
    const int lane = tid & 63;
    const int w = tid >> 6;
    const int row0 = blockIdx.x * 2;   // even -> both rows same batch
    const int b = row0 >> 5;

    if (tid < 128) {
        float4 v = ((const float4*)(Xd + (size_t)row0 * MEM))[tid];
        ((float4*)xrow0)[tid] = v;
    } else {
        float4 v = ((const float4*)(Xd + (size_t)(row0 + 1) * MEM))[tid - 128];
        ((float4*)xrow1)[tid - 128] = v;
    }
    __syncthreads();

    float s0 = 0.f, s1 = 0.f;
#pragma unroll
    for (int dd = 0; dd < 2; ++dd) {
        const int d = dd * 256 + tid;
        const float4* W = (const float4*)(Wm2 + (size_t)d * MEM);
        float a0 = 0.f, a1 = 0.f;
#pragma unroll 8
        for (int k4 = 0; k4 < 128; ++k4) {
            float4 wv = W[k4];
            float4 x0 = ((const float4*)xrow0)[k4];
            float4 x1 = ((const float4*)xrow1)[k4];
            a0 = fmaf(wv.x, x0.x, a0); a1 = fmaf(wv.x, x1.x, a1);
            a0 = fmaf(wv.y, x0.y, a0); a1 = fmaf(wv.y, x1.y, a1);
            a0 = fmaf(wv.z, x0.z, a0); a1 = fmaf(wv.z, x1.z, a1);
            a0 = fmaf(wv.w, x0.w, a0); a1 = fmaf(wv.w, x1.w, a1);
        }
        const float wvd = Wv2[d];
        const float bsd = bias2[b * DEC + d];
        s0 = fmaf(wvd, fast_tanh(a0 + bsd), s0);
        s1 = fmaf(wvd, fast_tanh(a1 + bsd), s1);
    }
    // block reduce: wave shuffle then cross-wave LDS
#pragma unroll
    for (int o = 1; o <= 32; o <<= 1) {
        s0 += __shfl_xor(s0, o);
        s1 += __shfl_xor(s1, o);
    }
    if (lane == 0) { wsum[0][w] = s0; wsum[1][w] = s1; }
    __syncthreads();
    if (tid < 2) {
        float s = wsum[tid][0] + wsum[tid][1] + wsum[tid][2] + wsum[tid][3];
        doc_scores[row0 + tid] = s;
    }
}

// ============ fused word kernel (R0-verified, 107 us): byte-identical control ============
__global__ __launch_bounds__(512) void fused_word_kernel(
    const float* __restrict__ X,            // word_memory [65536][512]
    const unsigned short* __restrict__ Wp,  // permuted bf16 Wm
    const float* __restrict__ Wv,           // [512]
    const float* __restrict__ bias1,        // [16][512]
    const float* __restrict__ doc_scores,   // [512]
    const int* __restrict__ doc_mask,       // [512]
    const int* __restrict__ word_mask,      // [65536]
    float* __restrict__ rescaled_out,       // d_out + 8192
    float* __restrict__ ctx_out)            // d_out [16][512], pre-zeroed, atomic
{
    __shared__ __align__(16) short lsA[2 * 2048];   // 2 x 4KB double buffer
    __shared__ float red[8][128];
    __shared__ float sS[128];
    __shared__ float rmax2[2], rsum2[2];
    __shared__ float s_dattn;
    __shared__ __align__(16) float4 part[3 * 128];

    const int tid = threadIdx.x;
    const int lane = tid & 63;
    const int wid = tid >> 6;          // 0..7
    const int bq = blockIdx.x;         // 0..511
    const int r0 = bq * L2;            // first word row
    const int b = bq >> 5;
    const int q = bq & 31;

    // ---- doc softmax for this block's (b,q): one scalar ----
    if (tid < 32) {
        int di = b * 32 + tid;
        float dsv = doc_scores[di];
        if (doc_mask[di] == 0) dsv = -INFINITY;
        float mx = dsv;
#pragma unroll
        for (int o = 1; o <= 16; o <<= 1) mx = fmaxf(mx, __shfl_xor(mx, o));
        float e = __expf(dsv - mx);
        float sum = e;
#pragma unroll
        for (int o = 1; o <= 16; o <<= 1) sum += __shfl_xor(sum, o);
        if (tid == q) s_dattn = e / sum;
    }

    // ---- A staging map: thread -> (row, kq) ----
    const int row = tid >> 2;          // 0..127
    const int kq = tid & 3;            // float4 index within 16-k chunk
    const int mt_s = row >> 5;
    const int rl_s = row & 31;
    const int k8_s = kq >> 1;
    const int q4 = (kq & 1) * 4;       // short offset within slot
    const int slot_s = mt_s * 64 + k8_s * 32 + rl_s;
    const float4* xs = (const float4*)(X + (size_t)(r0 + row) * DEC) + kq;

    const uint4* Bp = (const uint4*)Wp;
    const int boff = wid * 128 + lane;

    f32x16 acc[8];   // [mt*2 + nt]
#pragma unroll
    for (int t = 0; t < 8; ++t)
        acc[t] = (f32x16){0.f,0.f,0.f,0.f, 0.f,0.f,0.f,0.f, 0.f,0.f,0.f,0.f, 0.f,0.f,0.f,0.f};

    const short8* lA = (const short8*)lsA;

    // ---- deep prefetch: A chunks 0..3, B chunks 0..1 ----
    float4 va[4];
#pragma unroll
    for (int i = 0; i < 4; ++i) va[i] = xs[i * 4];
    uint4 ub0[2], ub1[2];
#pragma unroll
    for (int i = 0; i < 2; ++i) {
        ub0[i] = Bp[i * 1024 + boff];
        ub1[i] = Bp[i * 1024 + boff + 64];
    }

#pragma unroll
    for (int c = 0; c < 32; ++c) {
        const int p = c & 1;
        const int ia = c & 3;
        // write A chunk c into buffer p (waits vmcnt for va[ia], issued 4 iters ago)
        uint2 w2;
        w2.x = pkbf(va[ia].x, va[ia].y);
        w2.y = pkbf(va[ia].z, va[ia].w);
        *(uint2*)&lsA[(p * 256 + slot_s) * 8 + q4] = w2;
        __syncthreads();

        // refill prefetch: A 4 ahead, B 2 ahead (wrap -> dead-but-valid loads)
        va[ia] = xs[((c + 4) & 31) * 4];
        uint4 nb0 = Bp[((c + 2) & 31) * 1024 + boff];
        uint4 nb1 = Bp[((c + 2) & 31) * 1024 + boff + 64];

        short8 a0 = lA[p * 256 + 0 * 64 + lane];
        short8 a1 = lA[p * 256 + 1 * 64 + lane];
        short8 a2 = lA[p * 256 + 2 * 64 + lane];
        short8 a3 = lA[p * 256 + 3 * 64 + lane];
        union { uint4 u; short8 s; } cb0{ub0[p]}, cb1{ub1[p]};
        acc[0] = __builtin_amdgcn_mfma_f32_32x32x16_bf16(a0, cb0.s, acc[0], 0, 0, 0);
        acc[1] = __builtin_amdgcn_mfma_f32_32x32x16_bf16(a0, cb1.s, acc[1], 0, 0, 0);
        acc[2] = __builtin_amdgcn_mfma_f32_32x32x16_bf16(a1, cb0.s, acc[2], 0, 0, 0);
        acc[3] = __builtin_amdgcn_mfma_f32_32x32x16_bf16(a1, cb1.s, acc[3], 0, 0, 0);
        acc[4] = __builtin_amdgcn_mfma_f32_32x32x16_bf16(a2, cb0.s, acc[4], 0, 0, 0);
        acc[5] = __builtin_amdgcn_mfma_f32_32x32x16_bf16(a2, cb1.s, acc[5], 0, 0, 0);
        acc[6] = __builtin_amdgcn_mfma_f32_32x32x16_bf16(a3, cb0.s, acc[6], 0, 0, 0);
        acc[7] = __builtin_amdgcn_mfma_f32_32x32x16_bf16(a3, cb1.s, acc[7], 0, 0, 0);

        ub0[p] = nb0; ub1[p] = nb1;
    }

    // ---- epilogue: tanh + Wv partial over this wave's 64 d ----
    // C/D layout (32x32, HW-verified): col = lane&31, row_in = (r&3) + 8*(r>>2) + 4*(lane>>5)
    const int col = lane & 31;
    const int h = lane >> 5;
    float wv0, wv1, bs0, bs1;
    {
        int d0 = wid * 64 + col;
        int d1 = wid * 64 + 32 + col;
        wv0 = Wv[d0]; wv1 = Wv[d1];
        bs0 = bias1[b * DEC + d0]; bs1 = bias1[b * DEC + d1];
    }
#pragma unroll
    for (int mt = 0; mt < 4; ++mt) {
#pragma unroll
        for (int r = 0; r < 16; ++r) {
            float p = fmaf(wv0, fast_tanh(acc[mt * 2 + 0][r] + bs0),
                           wv1 * fast_tanh(acc[mt * 2 + 1][r] + bs1));
            p += __shfl_xor(p, 16);
            p += __shfl_xor(p, 8);
            p += __shfl_xor(p, 4);
            p += __shfl_xor(p, 2);
            p += __shfl_xor(p, 1);
            if (col == r) {
                int row_in = (r & 3) + 8 * (r >> 2) + 4 * h;
                red[wid][mt * 32 + row_in] = p;
            }
        }
    }
    __syncthreads();

    // ---- block softmax over 128 words (threads 0..127) ----
    float e = 0.f, sv = 0.f;
    if (tid < 128) {
        sv = red[0][tid] + red[1][tid] + red[2][tid] + red[3][tid]
           + red[4][tid] + red[5][tid] + red[6][tid] + red[7][tid];
        if (word_mask[r0 + tid] == 0) sv = -INFINITY;
        float mx = sv;
#pragma unroll
        for (int o = 1; o <= 32; o <<= 1) mx = fmaxf(mx, __shfl_xor(mx, o));
        if (lane == 0) rmax2[wid] = mx;
    }
    __syncthreads();
    if (tid < 128) {
        float mx = fmaxf(rmax2[0], rmax2[1]);
        e = __expf(sv - mx);
        float sum = e;
#pragma unroll
        for (int o = 1; o <= 32; o <<= 1) sum += __shfl_xor(sum, o);
        if (lane == 0) rsum2[wid] = sum;
    }
    __syncthreads();
    if (tid < 128) {
        float sum = rsum2[0] + rsum2[1];
        float resc = s_dattn * (e / sum);
        sS[tid] = resc;
        rescaled_out[r0 + tid] = resc;
    }
    __syncthreads();

    // ---- context partial (fp32 X re-read, L2-hot) + atomic accumulate ----
    const int hh = tid >> 7;          // 0..3: w-group of 32
    const int m4 = tid & 127;         // float4 index in m
    const float4* Xr = (const float4*)X + (size_t)r0 * 128 + (size_t)hh * 32 * 128 + m4;
    float4 a = {0.f, 0.f, 0.f, 0.f};
#pragma unroll 8
    for (int i = 0; i < 32; ++i) {
        float rr = sS[hh * 32 + i];
        float4 v = Xr[(size_t)i * 128];
        a.x = fmaf(rr, v.x, a.x);
        a.y = fmaf(rr, v.y, a.y);
        a.z = fmaf(rr, v.z, a.z);
        a.w = fmaf(rr, v.w, a.w);
    }
    if (hh) part[(hh - 1) * 128 + m4] = a;
    __syncthreads();
    if (hh == 0) {
        float4 p0 = part[m4], p1 = part[128 + m4], p2 = part[256 + m4];
        a.x += p0.x + p1.x + p2.x;
        a.y += p0.y + p1.y + p2.y;
        a.z += p0.z + p1.z + p2.z;
        a.w += p0.w + p1.w + p2.w;
        float* dst = ctx_out + (size_t)b * MEM + m4 * 4;
        atomicAdd(dst + 0, a.x);
        atomicAdd(dst + 1, a.y);
        atomicAdd(dst + 2, a.z);
        atomicAdd(dst + 3, a.w);
    }
}

extern "C" void kernel_launch(void* const* d_in, const int* in_sizes, int n_in,
                              void* d_out, int out_size, void* d_ws, size_t ws_size,
                              hipStream_t stream) {
    const float* decoder_state = (const float*)d_in[0];
    const float* doc_memory    = (const float*)d_in[1];
    const float* word_memory   = (const float*)d_in[2];
    const float* topic_dist    = (const float*)d_in[3];
    const int*   doc_mask      = (const int*)d_in[4];
    const int*   word_mask     = (const int*)d_in[5];
    const float* Wv  = (const float*)d_in[6];
    const float* Wd  = (const float*)d_in[7];
    const float* Wt  = (const float*)d_in[8];
    const float* Wm  = (const float*)d_in[9];
    const float* Wv2 = (const float*)d_in[10];
    const float* Wd2 = (const float*)d_in[11];
    const float* Wt2 = (const float*)d_in[12];
    const float* Wm2 = (const float*)d_in[13];

    float* ws = (float*)d_ws;
    unsigned short* Wp  = (unsigned short*)(ws + WS_WP);
    float* bias1       = ws + WS_BIAS1;
    float* bias2       = ws + WS_BIAS2;
    float* doc_scores  = ws + WS_DOCSC;

    float* ctx_out      = (float*)d_out;                 // [16][512]
    float* rescaled_out = (float*)d_out + BATCH * MEM;   // [16][32][128]

    setup_kernel<<<128 + 64 + 4, 256, 0, stream>>>(Wm, Wp,
                                                   decoder_state, topic_dist,
                                                   Wd, Wt, Wd2, Wt2, bias1, bias2, ctx_out);
    doc_score_kernel<<<256, 256, 0, stream>>>(doc_memory, Wm2, Wv2, bias2, doc_scores);
    fused_word_kernel<<<NBQ, 512, 0, stream>>>(word_memory, Wp, Wv, bias1,
                                               doc_scores, doc_mask, word_mask,
                                               rescaled_out, ctx_out);
}